// Round 10
// baseline (429.483 us; speedup 1.0000x reference)
//
#include <hip/hip_runtime.h>
#include <math.h>
#include <hip/hip_fp16.h>

#define N_NODES 100000
#define N_EDGES 3200000
#define EPS 1e-16f
#define BSH 10
#define BN 1024              /* nodes per bucket */
#define NBK 98               /* ceil(100000/1024) */
#define PE 16
#define PTILE (PE * 256)

static __device__ __forceinline__ unsigned short f_to_bf(float f) {
    unsigned u = __float_as_uint(f);
    unsigned r = (u + 0x7FFFu + ((u >> 16) & 1u)) >> 16;  // RNE
    return (unsigned short)r;
}
// unpack w from slot: high 15 bits = positive f16 bits
static __device__ __forceinline__ float slot_w(unsigned s) {
    return __half2float(__ushort_as_half((unsigned short)(s >> 17)));
}
static __device__ __forceinline__ void fma8(float w, uint4 r, float* a) {
    a[0] = fmaf(w, __uint_as_float(r.x << 16), a[0]);
    a[1] = fmaf(w, __uint_as_float(r.x & 0xFFFF0000u), a[1]);
    a[2] = fmaf(w, __uint_as_float(r.y << 16), a[2]);
    a[3] = fmaf(w, __uint_as_float(r.y & 0xFFFF0000u), a[3]);
    a[4] = fmaf(w, __uint_as_float(r.z << 16), a[4]);
    a[5] = fmaf(w, __uint_as_float(r.z & 0xFFFF0000u), a[5]);
    a[6] = fmaf(w, __uint_as_float(r.w << 16), a[6]);
    a[7] = fmaf(w, __uint_as_float(r.w & 0xFFFF0000u), a[7]);
}
static __device__ __forceinline__ uint4 pack8(const float* a) {
    uint4 o;
    o.x = (unsigned)f_to_bf(a[0]) | ((unsigned)f_to_bf(a[1]) << 16);
    o.y = (unsigned)f_to_bf(a[2]) | ((unsigned)f_to_bf(a[3]) << 16);
    o.z = (unsigned)f_to_bf(a[4]) | ((unsigned)f_to_bf(a[5]) << 16);
    o.w = (unsigned)f_to_bf(a[6]) | ((unsigned)f_to_bf(a[7]) << 16);
    return o;
}

// ---- Phase A: exact bucket histograms ----
__global__ void hist_kernel(const int* __restrict__ ei,
                            unsigned* __restrict__ cnt_t, unsigned* __restrict__ cnt_f) {
    __shared__ unsigned ht[NBK], hf[NBK];
    for (int i = threadIdx.x; i < NBK; i += 256) { ht[i] = 0; hf[i] = 0; }
    __syncthreads();
    int stride = gridDim.x * blockDim.x;
    for (int e = blockIdx.x * blockDim.x + threadIdx.x; e < N_EDGES; e += stride) {
        atomicAdd(&hf[((unsigned)ei[e]) >> BSH], 1u);
        atomicAdd(&ht[((unsigned)ei[N_EDGES + e]) >> BSH], 1u);
    }
    __syncthreads();
    for (int i = threadIdx.x; i < NBK; i += 256) {
        if (ht[i]) atomicAdd(&cnt_t[i], ht[i]);
        if (hf[i]) atomicAdd(&cnt_f[i], hf[i]);
    }
}

// ---- Phase B: exclusive scan of bucket counts -> bases + reservation cursors ----
__global__ void scan_buckets(const unsigned* __restrict__ cnt_t, const unsigned* __restrict__ cnt_f,
                             unsigned* __restrict__ base_t, unsigned* __restrict__ base_f,
                             unsigned* __restrict__ pos_t, unsigned* __restrict__ pos_f) {
    __shared__ unsigned sc[128];
    int tid = threadIdx.x;
    if (tid < 128) {
        unsigned own = (tid < NBK) ? cnt_t[tid] : 0u;
        sc[tid] = own;
        __syncthreads();
        for (int o = 1; o < 128; o <<= 1) {
            unsigned v = (tid >= o) ? sc[tid - o] : 0u;
            __syncthreads();
            sc[tid] += v;
            __syncthreads();
        }
        if (tid < NBK) { unsigned ex = sc[tid] - own; base_t[tid] = ex; pos_t[tid] = ex; }
        if (tid == NBK - 1) base_t[NBK] = sc[tid];
        __syncthreads();
        own = (tid < NBK) ? cnt_f[tid] : 0u;
        sc[tid] = own;
        __syncthreads();
        for (int o = 1; o < 128; o <<= 1) {
            unsigned v = (tid >= o) ? sc[tid - o] : 0u;
            __syncthreads();
            sc[tid] += v;
            __syncthreads();
        }
        if (tid < NBK) { unsigned ex = sc[tid] - own; base_f[tid] = ex; pos_f[tid] = ex; }
        if (tid == NBK - 1) base_f[NBK] = sc[tid];
    }
}

// ---- Phase C: single-pass partition (register-staged tile).
// bt: uint2 (f | t_local<<17, ex f32). bf: u32 (f_local<<16 | f16(ex)). ----
__global__ void partition(const int* __restrict__ ei, const float* __restrict__ attr,
                          unsigned* __restrict__ pos_t, unsigned* __restrict__ pos_f,
                          uint2* __restrict__ bt, unsigned* __restrict__ bf) {
    __shared__ unsigned ht[NBK], hf[NBK];
    for (int i = threadIdx.x; i < NBK; i += 256) { ht[i] = 0; hf[i] = 0; }
    __syncthreads();
    const int tile = blockIdx.x * PTILE;
    unsigned fv[PE], tv[PE];
    float xv[PE];
    #pragma unroll
    for (int k = 0; k < PE; ++k) {
        int e = tile + k * 256 + threadIdx.x;
        if (e < N_EDGES) {
            fv[k] = (unsigned)ei[e];
            tv[k] = (unsigned)ei[N_EDGES + e];
            xv[k] = __expf(attr[e]);
            atomicAdd(&ht[tv[k] >> BSH], 1u);
            atomicAdd(&hf[fv[k] >> BSH], 1u);
        } else {
            tv[k] = 0xFFFFFFFFu;
        }
    }
    __syncthreads();
    for (int i = threadIdx.x; i < NBK; i += 256) {
        unsigned c = ht[i];
        if (c) ht[i] = atomicAdd(&pos_t[i], c);
        c = hf[i];
        if (c) hf[i] = atomicAdd(&pos_f[i], c);
    }
    __syncthreads();
    #pragma unroll
    for (int k = 0; k < PE; ++k) {
        if (tv[k] != 0xFFFFFFFFu) {
            unsigned p = atomicAdd(&ht[tv[k] >> BSH], 1u);
            bt[p] = make_uint2(fv[k] | ((tv[k] & (BN - 1u)) << 17), __float_as_uint(xv[k]));
            unsigned q = atomicAdd(&hf[fv[k] >> BSH], 1u);
            bf[q] = ((fv[k] & (BN - 1u)) << 16) |
                    (unsigned)__half_as_ushort(__float2half(xv[k]));
        }
    }
}

// ---- Phase D: per-src-bucket sums -> s_from_inv ----
__global__ void bucket_sum_f(const unsigned* __restrict__ base_f, const unsigned* __restrict__ bf,
                             float* __restrict__ s_from_inv) {
    __shared__ float s[BN];
    int b = blockIdx.x, tid = threadIdx.x;
    #pragma unroll
    for (int j = 0; j < BN / 256; ++j) s[tid + j * 256] = 0.f;
    __syncthreads();
    unsigned lo = base_f[b], hi = base_f[b + 1];
    for (unsigned i = lo + tid; i < hi; i += 256) {
        unsigned u = bf[i];
        atomicAdd(&s[u >> 16], __half2float(__ushort_as_half((unsigned short)(u & 0xFFFFu))));
    }
    __syncthreads();
    #pragma unroll
    for (int j = 0; j < BN / 256; ++j) {
        int node = b * BN + tid + j * 256;
        if (node < N_NODES) s_from_inv[node] = rsqrtf(s[tid + j * 256] + EPS);
    }
}

// ---- Phase E: per-dst-bucket: dense CSR (row_ptr) + packed 4B edge slots ----
__global__ void bucket_csr_t(const unsigned* __restrict__ base_t, const uint2* __restrict__ bt,
                             const float* __restrict__ s_from_inv,
                             unsigned* __restrict__ row_ptr, unsigned* __restrict__ slots) {
    __shared__ unsigned cnt[BN];
    __shared__ float sto[BN];
    __shared__ float rs[BN];
    __shared__ unsigned cur[BN];
    __shared__ unsigned sc[256];
    int b = blockIdx.x, tid = threadIdx.x;
    #pragma unroll
    for (int j = 0; j < BN / 256; ++j) { cnt[tid + j * 256] = 0; sto[tid + j * 256] = 0.f; }
    __syncthreads();
    unsigned lo = base_t[b], hi = base_t[b + 1];
    for (unsigned i = lo + tid; i < hi; i += 256) {
        uint2 u = bt[i];
        unsigned tl = u.x >> 17;
        atomicAdd(&cnt[tl], 1u);
        atomicAdd(&sto[tl], __uint_as_float(u.y));
    }
    __syncthreads();
    // hierarchical exclusive scan: thread tid owns entries [tid*4, tid*4+4)
    unsigned c0 = cnt[tid * 4], c1 = cnt[tid * 4 + 1], c2 = cnt[tid * 4 + 2], c3 = cnt[tid * 4 + 3];
    unsigned tot = c0 + c1 + c2 + c3;
    sc[tid] = tot;
    __syncthreads();
    for (int o = 1; o < 256; o <<= 1) {
        unsigned v = (tid >= o) ? sc[tid - o] : 0u;
        __syncthreads();
        sc[tid] += v;
        __syncthreads();
    }
    unsigned run = lo + sc[tid] - tot;
    int node0 = b * BN + tid * 4;
    unsigned bases[4] = {run, run + c0, run + c0 + c1, run + c0 + c1 + c2};
    #pragma unroll
    for (int j = 0; j < 4; ++j) {
        if (node0 + j < N_NODES) row_ptr[node0 + j] = bases[j];
        cur[tid * 4 + j] = bases[j];
    }
    if (b == NBK - 1 && tid == 0) row_ptr[N_NODES] = N_EDGES;
    #pragma unroll
    for (int j = 0; j < BN / 256; ++j) {
        int i = tid + j * 256;
        rs[i] = rsqrtf(sto[i] + EPS);
    }
    __syncthreads();
    for (unsigned i = lo + tid; i < hi; i += 256) {
        uint2 u = bt[i];
        unsigned tl = u.x >> 17;
        unsigned f = u.x & 0x1FFFFu;
        float w = __uint_as_float(u.y) * rs[tl] * s_from_inv[f];
        unsigned hb = (unsigned)__half_as_ushort(__float2half(w));  // w>=0: bit15==0
        unsigned p = atomicAdd(&cur[tl], 1u);
        slots[p] = f | (hb << 17);
    }
}

// ---- emb -> bf16 table (uint4 rows) + out_emb copy ----
__global__ void emb_cvt(const float4* __restrict__ emb4, float4* __restrict__ out_emb4,
                        uint4* __restrict__ emb_bf) {
    int i = blockIdx.x * blockDim.x + threadIdx.x;
    if (i >= N_NODES * 8) return;
    float4 v0 = emb4[2 * i], v1 = emb4[2 * i + 1];
    out_emb4[2 * i] = v0;
    out_emb4[2 * i + 1] = v1;
    float a[8] = {v0.x, v0.y, v0.z, v0.w, v1.x, v1.y, v1.z, v1.w};
    emb_bf[i] = pack8(a);
}

// 4x-unrolled gather core: 8 lanes/node, 16B row-slices, dual accumulators
#define GATHER_CORE(TABLE)                                                        \
    float a[8] = {0, 0, 0, 0, 0, 0, 0, 0};                                        \
    float bacc[8] = {0, 0, 0, 0, 0, 0, 0, 0};                                     \
    unsigned k = beg;                                                             \
    for (; k + 4 <= end; k += 4) {                                                \
        unsigned s0 = slots[k], s1 = slots[k + 1], s2 = slots[k + 2], s3 = slots[k + 3]; \
        uint4 r0 = TABLE[(size_t)(s0 & 0x1FFFFu) * 8 + lane];                     \
        uint4 r1 = TABLE[(size_t)(s1 & 0x1FFFFu) * 8 + lane];                     \
        uint4 r2 = TABLE[(size_t)(s2 & 0x1FFFFu) * 8 + lane];                     \
        uint4 r3 = TABLE[(size_t)(s3 & 0x1FFFFu) * 8 + lane];                     \
        fma8(slot_w(s0), r0, a);                                                  \
        fma8(slot_w(s1), r1, bacc);                                               \
        fma8(slot_w(s2), r2, a);                                                  \
        fma8(slot_w(s3), r3, bacc);                                               \
    }                                                                             \
    for (; k < end; ++k) {                                                        \
        unsigned s = slots[k];                                                    \
        uint4 r = TABLE[(size_t)(s & 0x1FFFFu) * 8 + lane];                       \
        fma8(slot_w(s), r, a);                                                    \
    }                                                                             \
    _Pragma("unroll")                                                             \
    for (int j = 0; j < 8; ++j) a[j] += bacc[j];

// ---- Layer 1: gather emb_bf; T1 = bf16(l1); acc = emb + l1 (f32, write-only) ----
__global__ void prop1(const unsigned* __restrict__ row_ptr, const unsigned* __restrict__ slots,
                      const uint4* __restrict__ emb_bf, const float4* __restrict__ emb4,
                      uint4* __restrict__ T1, float4* __restrict__ acc) {
    int node = blockIdx.x * 32 + (threadIdx.x >> 3);
    int lane = threadIdx.x & 7;
    if (node >= N_NODES) return;
    unsigned beg = row_ptr[node], end = row_ptr[node + 1];
    GATHER_CORE(emb_bf)
    size_t o = (size_t)node * 8 + lane;
    T1[o] = pack8(a);
    size_t o4 = (size_t)node * 16 + lane * 2;
    float4 e0 = emb4[o4], e1 = emb4[o4 + 1];
    acc[o4]     = make_float4(e0.x + a[0], e0.y + a[1], e0.z + a[2], e0.w + a[3]);
    acc[o4 + 1] = make_float4(e1.x + a[4], e1.y + a[5], e1.z + a[6], e1.w + a[7]);
}

// ---- Layer 2: gather T1 -> T2 only (acc deferred) ----
__global__ void prop2(const unsigned* __restrict__ row_ptr, const unsigned* __restrict__ slots,
                      const uint4* __restrict__ T1, uint4* __restrict__ T2) {
    int node = blockIdx.x * 32 + (threadIdx.x >> 3);
    int lane = threadIdx.x & 7;
    if (node >= N_NODES) return;
    unsigned beg = row_ptr[node], end = row_ptr[node + 1];
    GATHER_CORE(T1)
    T2[(size_t)node * 8 + lane] = pack8(a);
}

// ---- Layer 3: gather T2; acc = (acc + T2[own] + l3) * 0.25 ----
__global__ void prop3(const unsigned* __restrict__ row_ptr, const unsigned* __restrict__ slots,
                      const uint4* __restrict__ T2, float4* __restrict__ acc) {
    int node = blockIdx.x * 32 + (threadIdx.x >> 3);
    int lane = threadIdx.x & 7;
    if (node >= N_NODES) return;
    unsigned beg = row_ptr[node], end = row_ptr[node + 1];
    GATHER_CORE(T2)
    size_t o = (size_t)node * 8 + lane;
    uint4 l2 = T2[o];
    float l[8] = {
        __uint_as_float(l2.x << 16), __uint_as_float(l2.x & 0xFFFF0000u),
        __uint_as_float(l2.y << 16), __uint_as_float(l2.y & 0xFFFF0000u),
        __uint_as_float(l2.z << 16), __uint_as_float(l2.z & 0xFFFF0000u),
        __uint_as_float(l2.w << 16), __uint_as_float(l2.w & 0xFFFF0000u)};
    size_t o4 = (size_t)node * 16 + lane * 2;
    float4 c0 = acc[o4], c1 = acc[o4 + 1];
    acc[o4]     = make_float4((c0.x + l[0] + a[0]) * 0.25f, (c0.y + l[1] + a[1]) * 0.25f,
                              (c0.z + l[2] + a[2]) * 0.25f, (c0.w + l[3] + a[3]) * 0.25f);
    acc[o4 + 1] = make_float4((c1.x + l[4] + a[4]) * 0.25f, (c1.y + l[5] + a[5]) * 0.25f,
                              (c1.z + l[6] + a[6]) * 0.25f, (c1.w + l[7] + a[7]) * 0.25f);
}

extern "C" void kernel_launch(void* const* d_in, const int* in_sizes, int n_in,
                              void* d_out, int out_size, void* d_ws, size_t ws_size,
                              hipStream_t stream) {
    const float* emb = (const float*)d_in[0];
    const int* ei = (const int*)d_in[1];
    const float* attr = (const float*)d_in[2];

    float* out_emb = (float*)d_out;
    float* out_acc = out_emb + (size_t)N_NODES * 64;

    char* ws = (char*)d_ws;
    size_t off = 0;
    auto alloc = [&](size_t bytes) -> void* {
        void* p = ws + off;
        off += (bytes + 255) & ~(size_t)255;
        return p;
    };
    unsigned* cnt_t   = (unsigned*)alloc((size_t)NBK * 4);
    unsigned* cnt_f   = (unsigned*)alloc((size_t)NBK * 4);
    size_t zero_bytes = off;
    unsigned* base_t  = (unsigned*)alloc((size_t)(NBK + 1) * 4);
    unsigned* base_f  = (unsigned*)alloc((size_t)(NBK + 1) * 4);
    unsigned* pos_t   = (unsigned*)alloc((size_t)NBK * 4);
    unsigned* pos_f   = (unsigned*)alloc((size_t)NBK * 4);
    unsigned* row_ptr = (unsigned*)alloc((size_t)(N_NODES + 1) * 4);
    float* s_from_inv = (float*)   alloc((size_t)N_NODES * 4);
    uint2* bt         = (uint2*)   alloc((size_t)N_EDGES * 8);   // dead after bucket_csr_t
    unsigned* bfa     = (unsigned*)alloc((size_t)N_EDGES * 4);   // dead after bucket_sum_f
    unsigned* slots   = (unsigned*)alloc((size_t)N_EDGES * 4);   // packed f|w
    uint4* T1         = (uint4*)   alloc((size_t)N_NODES * 128); // bf16 rows
    // aliases inside the dead bt region (25.6MB = two 12.8MB tables):
    uint4* T2     = (uint4*)bt;
    uint4* emb_bf = (uint4*)((char*)bt + (size_t)N_NODES * 128);
    (void)ws_size;

    hipMemsetAsync(d_ws, 0, zero_bytes, stream);

    hist_kernel<<<256, 256, 0, stream>>>(ei, cnt_t, cnt_f);
    scan_buckets<<<1, 128, 0, stream>>>(cnt_t, cnt_f, base_t, base_f, pos_t, pos_f);
    const int pblocks = (N_EDGES + PTILE - 1) / PTILE;
    partition<<<pblocks, 256, 0, stream>>>(ei, attr, pos_t, pos_f, bt, bfa);
    bucket_sum_f<<<NBK, 256, 0, stream>>>(base_f, bfa, s_from_inv);
    bucket_csr_t<<<NBK, 256, 0, stream>>>(base_t, bt, s_from_inv, row_ptr, slots);

    const int vgrid = (N_NODES * 8 + 255) / 256;
    emb_cvt<<<vgrid, 256, 0, stream>>>((const float4*)emb, (float4*)out_emb, emb_bf);

    const int pgrid = (N_NODES * 8 + 255) / 256;
    prop1<<<pgrid, 256, 0, stream>>>(row_ptr, slots, emb_bf, (const float4*)emb,
                                     T1, (float4*)out_acc);
    prop2<<<pgrid, 256, 0, stream>>>(row_ptr, slots, T1, T2);
    prop3<<<pgrid, 256, 0, stream>>>(row_ptr, slots, T2, (float4*)out_acc);
}

// Round 11
// 372.784 us; speedup vs baseline: 1.1521x; 1.1521x over previous
//
#include <hip/hip_runtime.h>
#include <math.h>
#include <hip/hip_fp16.h>

#define N_NODES 100000
#define N_EDGES 3200000
#define EPS 1e-16f
#define BSH 8
#define BN 256               /* nodes per bucket */
#define NBK 391              /* ceil(100000/256) */
#define PE 16
#define PTILE (PE * 256)

static __device__ __forceinline__ unsigned short f_to_bf(float f) {
    unsigned u = __float_as_uint(f);
    unsigned r = (u + 0x7FFFu + ((u >> 16) & 1u)) >> 16;  // RNE
    return (unsigned short)r;
}
// unpack w from slot: high 15 bits = positive f16 bits
static __device__ __forceinline__ float slot_w(unsigned s) {
    return __half2float(__ushort_as_half((unsigned short)(s >> 17)));
}
static __device__ __forceinline__ void fma8(float w, uint4 r, float* a) {
    a[0] = fmaf(w, __uint_as_float(r.x << 16), a[0]);
    a[1] = fmaf(w, __uint_as_float(r.x & 0xFFFF0000u), a[1]);
    a[2] = fmaf(w, __uint_as_float(r.y << 16), a[2]);
    a[3] = fmaf(w, __uint_as_float(r.y & 0xFFFF0000u), a[3]);
    a[4] = fmaf(w, __uint_as_float(r.z << 16), a[4]);
    a[5] = fmaf(w, __uint_as_float(r.z & 0xFFFF0000u), a[5]);
    a[6] = fmaf(w, __uint_as_float(r.w << 16), a[6]);
    a[7] = fmaf(w, __uint_as_float(r.w & 0xFFFF0000u), a[7]);
}
static __device__ __forceinline__ uint4 pack8(const float* a) {
    uint4 o;
    o.x = (unsigned)f_to_bf(a[0]) | ((unsigned)f_to_bf(a[1]) << 16);
    o.y = (unsigned)f_to_bf(a[2]) | ((unsigned)f_to_bf(a[3]) << 16);
    o.z = (unsigned)f_to_bf(a[4]) | ((unsigned)f_to_bf(a[5]) << 16);
    o.w = (unsigned)f_to_bf(a[6]) | ((unsigned)f_to_bf(a[7]) << 16);
    return o;
}

// ---- Phase A: exact bucket histograms ----
__global__ void hist_kernel(const int* __restrict__ ei,
                            unsigned* __restrict__ cnt_t, unsigned* __restrict__ cnt_f) {
    __shared__ unsigned ht[NBK], hf[NBK];
    for (int i = threadIdx.x; i < NBK; i += 256) { ht[i] = 0; hf[i] = 0; }
    __syncthreads();
    int stride = gridDim.x * blockDim.x;
    for (int e = blockIdx.x * blockDim.x + threadIdx.x; e < N_EDGES; e += stride) {
        atomicAdd(&hf[((unsigned)ei[e]) >> BSH], 1u);
        atomicAdd(&ht[((unsigned)ei[N_EDGES + e]) >> BSH], 1u);
    }
    __syncthreads();
    for (int i = threadIdx.x; i < NBK; i += 256) {
        if (ht[i]) atomicAdd(&cnt_t[i], ht[i]);
        if (hf[i]) atomicAdd(&cnt_f[i], hf[i]);
    }
}

// ---- Phase B: exclusive scan of bucket counts -> bases + reservation cursors ----
__global__ void scan_buckets(const unsigned* __restrict__ cnt_t, const unsigned* __restrict__ cnt_f,
                             unsigned* __restrict__ base_t, unsigned* __restrict__ base_f,
                             unsigned* __restrict__ pos_t, unsigned* __restrict__ pos_f) {
    __shared__ unsigned sc[512];
    int tid = threadIdx.x;
    unsigned own = (tid < NBK) ? cnt_t[tid] : 0u;
    sc[tid] = own;
    __syncthreads();
    for (int o = 1; o < 512; o <<= 1) {
        unsigned v = (tid >= o) ? sc[tid - o] : 0u;
        __syncthreads();
        sc[tid] += v;
        __syncthreads();
    }
    if (tid < NBK) { unsigned ex = sc[tid] - own; base_t[tid] = ex; pos_t[tid] = ex; }
    if (tid == NBK - 1) base_t[NBK] = sc[tid];
    __syncthreads();
    own = (tid < NBK) ? cnt_f[tid] : 0u;
    sc[tid] = own;
    __syncthreads();
    for (int o = 1; o < 512; o <<= 1) {
        unsigned v = (tid >= o) ? sc[tid - o] : 0u;
        __syncthreads();
        sc[tid] += v;
        __syncthreads();
    }
    if (tid < NBK) { unsigned ex = sc[tid] - own; base_f[tid] = ex; pos_f[tid] = ex; }
    if (tid == NBK - 1) base_f[NBK] = sc[tid];
}

// ---- Phase C: single-pass partition (register-staged tile).
// bt: uint2 (f | t_local<<17, ex f32). bf: u32 (f_local<<16 | f16(ex)). ----
__global__ void partition(const int* __restrict__ ei, const float* __restrict__ attr,
                          unsigned* __restrict__ pos_t, unsigned* __restrict__ pos_f,
                          uint2* __restrict__ bt, unsigned* __restrict__ bf) {
    __shared__ unsigned ht[NBK], hf[NBK];
    for (int i = threadIdx.x; i < NBK; i += 256) { ht[i] = 0; hf[i] = 0; }
    __syncthreads();
    const int tile = blockIdx.x * PTILE;
    unsigned fv[PE], tv[PE];
    float xv[PE];
    #pragma unroll
    for (int k = 0; k < PE; ++k) {
        int e = tile + k * 256 + threadIdx.x;
        if (e < N_EDGES) {
            fv[k] = (unsigned)ei[e];
            tv[k] = (unsigned)ei[N_EDGES + e];
            xv[k] = __expf(attr[e]);
            atomicAdd(&ht[tv[k] >> BSH], 1u);
            atomicAdd(&hf[fv[k] >> BSH], 1u);
        } else {
            tv[k] = 0xFFFFFFFFu;
        }
    }
    __syncthreads();
    for (int i = threadIdx.x; i < NBK; i += 256) {
        unsigned c = ht[i];
        if (c) ht[i] = atomicAdd(&pos_t[i], c);
        c = hf[i];
        if (c) hf[i] = atomicAdd(&pos_f[i], c);
    }
    __syncthreads();
    #pragma unroll
    for (int k = 0; k < PE; ++k) {
        if (tv[k] != 0xFFFFFFFFu) {
            unsigned p = atomicAdd(&ht[tv[k] >> BSH], 1u);
            bt[p] = make_uint2(fv[k] | ((tv[k] & (BN - 1u)) << 17), __float_as_uint(xv[k]));
            unsigned q = atomicAdd(&hf[fv[k] >> BSH], 1u);
            bf[q] = ((fv[k] & (BN - 1u)) << 16) |
                    (unsigned)__half_as_ushort(__float2half(xv[k]));
        }
    }
}

// ---- Phase D: per-src-bucket sums -> s_from_inv (LDS only) ----
__global__ void bucket_sum_f(const unsigned* __restrict__ base_f, const unsigned* __restrict__ bf,
                             float* __restrict__ s_from_inv) {
    __shared__ float s[BN];
    int b = blockIdx.x, tid = threadIdx.x;
    s[tid] = 0.f;
    __syncthreads();
    unsigned lo = base_f[b], hi = base_f[b + 1];
    for (unsigned i = lo + tid; i < hi; i += 256) {
        unsigned u = bf[i];
        atomicAdd(&s[u >> 16], __half2float(__ushort_as_half((unsigned short)(u & 0xFFFFu))));
    }
    __syncthreads();
    int node = b * BN + tid;
    if (node < N_NODES) s_from_inv[node] = rsqrtf(s[tid] + EPS);
}

// ---- Phase E: per-dst-bucket: dense CSR (row_ptr) + packed 4B edge slots ----
__global__ void bucket_csr_t(const unsigned* __restrict__ base_t, const uint2* __restrict__ bt,
                             const float* __restrict__ s_from_inv,
                             unsigned* __restrict__ row_ptr, unsigned* __restrict__ slots) {
    __shared__ unsigned cnt[BN];
    __shared__ float sto[BN];
    __shared__ unsigned sc[BN];
    __shared__ float rs[BN];
    __shared__ unsigned cur[BN];
    int b = blockIdx.x, tid = threadIdx.x;
    cnt[tid] = 0;
    sto[tid] = 0.f;
    __syncthreads();
    unsigned lo = base_t[b], hi = base_t[b + 1];
    for (unsigned i = lo + tid; i < hi; i += 256) {
        uint2 u = bt[i];
        unsigned tl = u.x >> 17;
        atomicAdd(&cnt[tl], 1u);
        atomicAdd(&sto[tl], __uint_as_float(u.y));
    }
    __syncthreads();
    unsigned own = cnt[tid];
    sc[tid] = own;
    __syncthreads();
    for (int o = 1; o < 256; o <<= 1) {
        unsigned v = (tid >= o) ? sc[tid - o] : 0u;
        __syncthreads();
        sc[tid] += v;
        __syncthreads();
    }
    unsigned excl = sc[tid] - own;
    int node = b * BN + tid;
    if (node < N_NODES) row_ptr[node] = lo + excl;
    if (b == NBK - 1 && tid == 0) row_ptr[N_NODES] = N_EDGES;
    rs[tid] = rsqrtf(sto[tid] + EPS);
    cur[tid] = lo + excl;
    __syncthreads();
    for (unsigned i = lo + tid; i < hi; i += 256) {
        uint2 u = bt[i];
        unsigned tl = u.x >> 17;
        unsigned f = u.x & 0x1FFFFu;
        float w = __uint_as_float(u.y) * rs[tl] * s_from_inv[f];
        unsigned hb = (unsigned)__half_as_ushort(__float2half(w));  // w>=0: bit15==0
        unsigned p = atomicAdd(&cur[tl], 1u);
        slots[p] = f | (hb << 17);
    }
}

// ---- emb -> bf16 table (uint4 rows) + out_emb copy ----
__global__ void emb_cvt(const float4* __restrict__ emb4, float4* __restrict__ out_emb4,
                        uint4* __restrict__ emb_bf) {
    int i = blockIdx.x * blockDim.x + threadIdx.x;
    if (i >= N_NODES * 8) return;
    float4 v0 = emb4[2 * i], v1 = emb4[2 * i + 1];
    out_emb4[2 * i] = v0;
    out_emb4[2 * i + 1] = v1;
    float a[8] = {v0.x, v0.y, v0.z, v0.w, v1.x, v1.y, v1.z, v1.w};
    emb_bf[i] = pack8(a);
}

// 4x-unrolled gather core: 8 lanes/node, 16B row-slices, dual accumulators
#define GATHER_CORE(TABLE)                                                        \
    float a[8] = {0, 0, 0, 0, 0, 0, 0, 0};                                        \
    float bacc[8] = {0, 0, 0, 0, 0, 0, 0, 0};                                     \
    unsigned k = beg;                                                             \
    for (; k + 4 <= end; k += 4) {                                                \
        unsigned s0 = slots[k], s1 = slots[k + 1], s2 = slots[k + 2], s3 = slots[k + 3]; \
        uint4 r0 = TABLE[(size_t)(s0 & 0x1FFFFu) * 8 + lane];                     \
        uint4 r1 = TABLE[(size_t)(s1 & 0x1FFFFu) * 8 + lane];                     \
        uint4 r2 = TABLE[(size_t)(s2 & 0x1FFFFu) * 8 + lane];                     \
        uint4 r3 = TABLE[(size_t)(s3 & 0x1FFFFu) * 8 + lane];                     \
        fma8(slot_w(s0), r0, a);                                                  \
        fma8(slot_w(s1), r1, bacc);                                               \
        fma8(slot_w(s2), r2, a);                                                  \
        fma8(slot_w(s3), r3, bacc);                                               \
    }                                                                             \
    for (; k < end; ++k) {                                                        \
        unsigned s = slots[k];                                                    \
        uint4 r = TABLE[(size_t)(s & 0x1FFFFu) * 8 + lane];                       \
        fma8(slot_w(s), r, a);                                                    \
    }                                                                             \
    _Pragma("unroll")                                                             \
    for (int j = 0; j < 8; ++j) a[j] += bacc[j];

// ---- Layer 1: gather emb_bf; T1 = bf16(l1); acc = emb + l1 (f32, write-only) ----
__global__ void prop1(const unsigned* __restrict__ row_ptr, const unsigned* __restrict__ slots,
                      const uint4* __restrict__ emb_bf, const float4* __restrict__ emb4,
                      uint4* __restrict__ T1, float4* __restrict__ acc) {
    int node = blockIdx.x * 32 + (threadIdx.x >> 3);
    int lane = threadIdx.x & 7;
    if (node >= N_NODES) return;
    unsigned beg = row_ptr[node], end = row_ptr[node + 1];
    GATHER_CORE(emb_bf)
    size_t o = (size_t)node * 8 + lane;
    T1[o] = pack8(a);
    size_t o4 = (size_t)node * 16 + lane * 2;
    float4 e0 = emb4[o4], e1 = emb4[o4 + 1];
    acc[o4]     = make_float4(e0.x + a[0], e0.y + a[1], e0.z + a[2], e0.w + a[3]);
    acc[o4 + 1] = make_float4(e1.x + a[4], e1.y + a[5], e1.z + a[6], e1.w + a[7]);
}

// ---- Layer 2: gather T1 -> T2 only (acc deferred) ----
__global__ void prop2(const unsigned* __restrict__ row_ptr, const unsigned* __restrict__ slots,
                      const uint4* __restrict__ T1, uint4* __restrict__ T2) {
    int node = blockIdx.x * 32 + (threadIdx.x >> 3);
    int lane = threadIdx.x & 7;
    if (node >= N_NODES) return;
    unsigned beg = row_ptr[node], end = row_ptr[node + 1];
    GATHER_CORE(T1)
    T2[(size_t)node * 8 + lane] = pack8(a);
}

// ---- Layer 3: gather T2; acc = (acc + T2[own] + l3) * 0.25 ----
__global__ void prop3(const unsigned* __restrict__ row_ptr, const unsigned* __restrict__ slots,
                      const uint4* __restrict__ T2, float4* __restrict__ acc) {
    int node = blockIdx.x * 32 + (threadIdx.x >> 3);
    int lane = threadIdx.x & 7;
    if (node >= N_NODES) return;
    unsigned beg = row_ptr[node], end = row_ptr[node + 1];
    GATHER_CORE(T2)
    size_t o = (size_t)node * 8 + lane;
    uint4 l2 = T2[o];
    float l[8] = {
        __uint_as_float(l2.x << 16), __uint_as_float(l2.x & 0xFFFF0000u),
        __uint_as_float(l2.y << 16), __uint_as_float(l2.y & 0xFFFF0000u),
        __uint_as_float(l2.z << 16), __uint_as_float(l2.z & 0xFFFF0000u),
        __uint_as_float(l2.w << 16), __uint_as_float(l2.w & 0xFFFF0000u)};
    size_t o4 = (size_t)node * 16 + lane * 2;
    float4 c0 = acc[o4], c1 = acc[o4 + 1];
    acc[o4]     = make_float4((c0.x + l[0] + a[0]) * 0.25f, (c0.y + l[1] + a[1]) * 0.25f,
                              (c0.z + l[2] + a[2]) * 0.25f, (c0.w + l[3] + a[3]) * 0.25f);
    acc[o4 + 1] = make_float4((c1.x + l[4] + a[4]) * 0.25f, (c1.y + l[5] + a[5]) * 0.25f,
                              (c1.z + l[6] + a[6]) * 0.25f, (c1.w + l[7] + a[7]) * 0.25f);
}

extern "C" void kernel_launch(void* const* d_in, const int* in_sizes, int n_in,
                              void* d_out, int out_size, void* d_ws, size_t ws_size,
                              hipStream_t stream) {
    const float* emb = (const float*)d_in[0];
    const int* ei = (const int*)d_in[1];
    const float* attr = (const float*)d_in[2];

    float* out_emb = (float*)d_out;
    float* out_acc = out_emb + (size_t)N_NODES * 64;

    char* ws = (char*)d_ws;
    size_t off = 0;
    auto alloc = [&](size_t bytes) -> void* {
        void* p = ws + off;
        off += (bytes + 255) & ~(size_t)255;
        return p;
    };
    unsigned* cnt_t   = (unsigned*)alloc((size_t)NBK * 4);
    unsigned* cnt_f   = (unsigned*)alloc((size_t)NBK * 4);
    size_t zero_bytes = off;
    unsigned* base_t  = (unsigned*)alloc((size_t)(NBK + 1) * 4);
    unsigned* base_f  = (unsigned*)alloc((size_t)(NBK + 1) * 4);
    unsigned* pos_t   = (unsigned*)alloc((size_t)NBK * 4);
    unsigned* pos_f   = (unsigned*)alloc((size_t)NBK * 4);
    unsigned* row_ptr = (unsigned*)alloc((size_t)(N_NODES + 1) * 4);
    float* s_from_inv = (float*)   alloc((size_t)N_NODES * 4);
    uint2* bt         = (uint2*)   alloc((size_t)N_EDGES * 8);   // dead after bucket_csr_t
    unsigned* bfa     = (unsigned*)alloc((size_t)N_EDGES * 4);   // dead after bucket_sum_f
    unsigned* slots   = (unsigned*)alloc((size_t)N_EDGES * 4);   // packed f|w
    uint4* T1         = (uint4*)   alloc((size_t)N_NODES * 128); // bf16 rows
    // aliases inside the dead bt region (25.6MB = two 12.8MB tables):
    uint4* T2     = (uint4*)bt;
    uint4* emb_bf = (uint4*)((char*)bt + (size_t)N_NODES * 128);
    (void)ws_size;

    hipMemsetAsync(d_ws, 0, zero_bytes, stream);

    hist_kernel<<<256, 256, 0, stream>>>(ei, cnt_t, cnt_f);
    scan_buckets<<<1, 512, 0, stream>>>(cnt_t, cnt_f, base_t, base_f, pos_t, pos_f);
    const int pblocks = (N_EDGES + PTILE - 1) / PTILE;
    partition<<<pblocks, 256, 0, stream>>>(ei, attr, pos_t, pos_f, bt, bfa);
    bucket_sum_f<<<NBK, 256, 0, stream>>>(base_f, bfa, s_from_inv);
    bucket_csr_t<<<NBK, 256, 0, stream>>>(base_t, bt, s_from_inv, row_ptr, slots);

    const int vgrid = (N_NODES * 8 + 255) / 256;
    emb_cvt<<<vgrid, 256, 0, stream>>>((const float4*)emb, (float4*)out_emb, emb_bf);

    const int pgrid = (N_NODES * 8 + 255) / 256;
    prop1<<<pgrid, 256, 0, stream>>>(row_ptr, slots, emb_bf, (const float4*)emb,
                                     T1, (float4*)out_acc);
    prop2<<<pgrid, 256, 0, stream>>>(row_ptr, slots, T1, T2);
    prop3<<<pgrid, 256, 0, stream>>>(row_ptr, slots, T2, (float4*)out_acc);
}